// Round 1
// baseline (1323.083 us; speedup 1.0000x reference)
//
#include <hip/hip_runtime.h>

// RandomPooling2D: out[b,c,i,j] = x[b,c, 2*i + pick_i, 2*j + pick_j]
// B=16, C=64, H=W=512, OH=OW=256, stride=2, kernel=2 (pick_* in {0,1}).
//
// Layout constants (all powers of two):
//   W  = 512  (input row, floats)      H*W = 2^18
//   OH = 256, OW = 256, OW/4 = 64
// One thread produces 4 consecutive output columns (one float4 store) from
// 8 consecutive input floats (two aligned float4 loads). pick_j selects the
// even or odd 4 of those 8 via a wave-uniform branch.

__global__ __launch_bounds__(256) void RandomPooling2D_kernel(
    const float* __restrict__ x,
    const int* __restrict__ p_pick_i,
    const int* __restrict__ p_pick_j,
    float4* __restrict__ out)
{
    const int t = blockIdx.x * blockDim.x + threadIdx.x;
    // decompose: t = ((bc * 256) + i) * 64 + j4
    const int j4 = t & 63;          // output column group (4 cols each)
    const int i  = (t >> 6) & 255;  // output row
    const int bc = t >> 14;         // fused batch*channel index

    const int pick_i = *p_pick_i;   // uniform scalar loads
    const int pick_j = *p_pick_j;

    // input offset in floats: bc*H*W + (2i+pick_i)*W + 8*j4  (multiple of 8 -> 32B aligned)
    const size_t base = ((size_t)bc << 18) + ((size_t)((i << 1) + pick_i) << 9) + ((size_t)j4 << 3);
    const float4 a = *(const float4*)(x + base);      // input cols 8j4 .. 8j4+3
    const float4 b = *(const float4*)(x + base + 4);  // input cols 8j4+4 .. 8j4+7

    float4 o;
    if (pick_j == 0) {              // wave-uniform branch, no divergence
        o.x = a.x; o.y = a.z; o.z = b.x; o.w = b.z;   // even columns
    } else {
        o.x = a.y; o.y = a.w; o.z = b.y; o.w = b.w;   // odd columns
    }
    out[t] = o;
}

extern "C" void kernel_launch(void* const* d_in, const int* in_sizes, int n_in,
                              void* d_out, int out_size, void* d_ws, size_t ws_size,
                              hipStream_t stream)
{
    const float* x        = (const float*)d_in[0];
    const int*   p_pick_i = (const int*)d_in[1];
    const int*   p_pick_j = (const int*)d_in[2];
    float4*      out      = (float4*)d_out;

    // out_size = 16*64*256*256 = 4,194,304 float4 groups -> 16,777,216 threads
    const int n_vec4  = out_size / 4;            // 16,777,216
    const int block   = 256;
    const int grid    = n_vec4 / block;          // 65,536 blocks

    RandomPooling2D_kernel<<<grid, block, 0, stream>>>(x, p_pick_i, p_pick_j, out);
}